// Round 2
// baseline (281.500 us; speedup 1.0000x reference)
//
#include <hip/hip_runtime.h>

#define B_    1
#define N_    6
#define C_    80
#define D_    112
#define HF_   16
#define WF_   44
#define NX_   128
#define NY_   128
#define NZ_   1
#define BN_   (B_ * N_)
#define HW_   (HF_ * WF_)
#define NPIX_ (NZ_ * NX_ * NY_)     // 16384 voxels (B_=1)
#define P_    (BN_ * HW_)           // 4224 pixels
#define MAXR_ 112                   // max runs per pixel

// ---------------- 3x3 inverse (adjugate) ----------------
__device__ __forceinline__ void inv3(const float* m, float* o) {
    float a = m[0], b = m[1], c = m[2];
    float d = m[3], e = m[4], f = m[5];
    float g = m[6], h = m[7], i = m[8];
    float A  =  (e * i - f * h);
    float Bc = -(d * i - f * g);
    float Cc =  (d * h - e * g);
    float det = a * A + b * Bc + c * Cc;
    float id = 1.0f / det;
    o[0] = A * id;                  o[1] = -(b * i - c * h) * id;   o[2] =  (b * f - c * e) * id;
    o[3] = Bc * id;                 o[4] =  (a * i - c * g) * id;   o[5] = -(a * f - c * d) * id;
    o[6] = Cc * id;                 o[7] = -(a * h - b * g) * id;   o[8] =  (a * e - b * d) * id;
}

// ============ Phase 1: per-pixel softmax + geometry + run emit ============
// one block (128 threads) per (bn,h,w) pixel
__global__ __launch_bounds__(128) void pixel_kernel(
    const float* __restrict__ rots, const float* __restrict__ trans,
    const float* __restrict__ intrins, const float* __restrict__ post_rots,
    const float* __restrict__ post_trans,
    const float* __restrict__ img_feat, const float* __restrict__ depth_digit,
    float* __restrict__ featT, int2* __restrict__ runs,
    int* __restrict__ runcnt, int* __restrict__ hist)
{
    int blk = blockIdx.x;
    int w  = blk % WF_;
    int h  = (blk / WF_) % HF_;
    int bn = blk / HW_;
    int hw = h * WF_ + w;
    int pix = blk;
    int tid = threadIdx.x;

    __shared__ float sm[24];        // invPost[9], combine[9], post_trans[3], trans[3]
    __shared__ float s_prob[D_];
    __shared__ int   s_vox[D_];
    __shared__ float s_red[128];
    __shared__ int   s_scan[128];
    __shared__ int   s_runvox[D_];
    __shared__ float s_runw[D_];

    // thread 112 (idle in softmax, D_=112) builds the per-camera matrices
    if (tid == 112) {
        float ip[9], ii[9];
        inv3(post_rots + bn * 9, ip);
        inv3(intrins + bn * 9, ii);
        const float* ro = rots + bn * 9;
        #pragma unroll
        for (int r = 0; r < 3; ++r)
            #pragma unroll
            for (int c = 0; c < 3; ++c)
                sm[9 + r * 3 + c] = ro[r * 3 + 0] * ii[0 * 3 + c] +
                                    ro[r * 3 + 1] * ii[1 * 3 + c] +
                                    ro[r * 3 + 2] * ii[2 * 3 + c];
        #pragma unroll
        for (int k = 0; k < 9; ++k) sm[k] = ip[k];
        #pragma unroll
        for (int k = 0; k < 3; ++k) { sm[18 + k] = post_trans[bn * 3 + k]; sm[21 + k] = trans[bn * 3 + k]; }
    }

    // transpose img_feat -> pixel-major featT (consumed by gather_kernel)
    if (tid < C_) featT[(size_t)pix * C_ + tid] = img_feat[((size_t)bn * C_ + tid) * HW_ + hw];

    // ---- softmax over D bins ----
    float logit = -INFINITY;
    if (tid < D_) logit = depth_digit[((size_t)bn * D_ + tid) * HW_ + hw];
    s_red[tid] = logit;
    __syncthreads();                      // also publishes sm[]
    #pragma unroll
    for (int s = 64; s > 0; s >>= 1) {
        if (tid < s) s_red[tid] = fmaxf(s_red[tid], s_red[tid + s]);
        __syncthreads();
    }
    float mx = s_red[0];
    __syncthreads();
    float e = (tid < D_) ? __expf(logit - mx) : 0.0f;
    s_red[tid] = e;
    __syncthreads();
    #pragma unroll
    for (int s = 64; s > 0; s >>= 1) {
        if (tid < s) s_red[tid] += s_red[tid + s];
        __syncthreads();
    }
    float inv_sum = 1.0f / s_red[0];
    if (tid < D_) s_prob[tid] = e * inv_sum;

    // ---- geometry: voxel index per depth bin ----
    if (tid < D_) {
        float dval = 2.0f + 0.5f * (float)tid;
        float xs = (float)((double)w * (703.0 / 43.0));  // np.linspace(0,703,44)
        float ys = (float)((double)h * 17.0);            // np.linspace(0,255,16)
        const float* ip  = sm;
        const float* cmb = sm + 9;
        const float* pt  = sm + 18;
        const float* tr  = sm + 21;
        float p0x = xs - pt[0], p0y = ys - pt[1], p0z = dval - pt[2];
        float p1x = ip[0] * p0x + ip[1] * p0y + ip[2] * p0z;
        float p1y = ip[3] * p0x + ip[4] * p0y + ip[5] * p0z;
        float p1z = ip[6] * p0x + ip[7] * p0y + ip[8] * p0z;
        float qx = p1x * p1z, qy = p1y * p1z, qz = p1z;
        float rx = cmb[0] * qx + cmb[1] * qy + cmb[2] * qz + tr[0];
        float ry = cmb[3] * qx + cmb[4] * qy + cmb[5] * qz + tr[1];
        float rz = cmb[6] * qx + cmb[7] * qy + cmb[8] * qz + tr[2];
        const float lox = -50.8f - 0.4f;
        const float loy = -50.8f - 0.4f;
        const float loz = -10.0f;
        int ix = (int)((rx - lox) / 0.8f);   // trunc toward zero == astype(int32)
        int iy = (int)((ry - loy) / 0.8f);
        int iz = (int)((rz - loz) / 20.0f);
        bool val = (ix >= 0) && (ix < NX_) && (iy >= 0) && (iy < NY_) && (iz >= 0) && (iz < NZ_);
        s_vox[tid] = val ? ((iz * NX_ + ix) * NY_ + iy) : -1;
    }
    __syncthreads();

    // ---- run-length merge of consecutive same-voxel bins (parallel) ----
    int head = 0;
    if (tid < D_) {
        int v = s_vox[tid];
        if (v >= 0 && (tid == 0 || s_vox[tid - 1] != v)) head = 1;
    }
    s_scan[tid] = head;
    __syncthreads();
    #pragma unroll
    for (int s = 1; s < 128; s <<= 1) {   // Hillis-Steele inclusive scan
        int t = (tid >= s) ? s_scan[tid - s] : 0;
        __syncthreads();
        s_scan[tid] += t;
        __syncthreads();
    }
    int R = s_scan[127];

    if (head) {
        int rid = s_scan[tid] - 1;
        int v = s_vox[tid];
        float wsum = 0.0f;
        for (int d = tid; d < D_ && s_vox[d] == v; ++d) wsum += s_prob[d];
        s_runvox[rid] = v;
        s_runw[rid]  = wsum;
    }
    __syncthreads();

    if (tid == 0) runcnt[pix] = R;
    if (tid < R) {
        int v = s_runvox[tid];
        runs[(size_t)pix * MAXR_ + tid] = make_int2(v, __float_as_int(s_runw[tid]));
        atomicAdd(&hist[v], 1);
    }
}

// ============ Phase 2: exclusive scan of 16384-voxel histogram ============
__global__ __launch_bounds__(1024) void scan_kernel(const int* __restrict__ hist,
                                                    int* __restrict__ start,
                                                    int* __restrict__ cursor)
{
    __shared__ int s_sum[1024];
    int tid = threadIdx.x;
    int base = tid * 16;
    int loc[16];
    int s = 0;
    #pragma unroll
    for (int i = 0; i < 16; ++i) { loc[i] = s; s += hist[base + i]; }
    s_sum[tid] = s;
    __syncthreads();
    for (int off = 1; off < 1024; off <<= 1) {
        int t = (tid >= off) ? s_sum[tid - off] : 0;
        __syncthreads();
        s_sum[tid] += t;
        __syncthreads();
    }
    int prev = (tid == 0) ? 0 : s_sum[tid - 1];
    #pragma unroll
    for (int i = 0; i < 16; ++i) {
        int val = prev + loc[i];
        start[base + i] = val;
        cursor[base + i] = val;
    }
    if (tid == 1023) start[NPIX_] = s_sum[1023];
}

// ============ Phase 3: counting-sort runs into CSR by voxel ============
__global__ __launch_bounds__(256) void sortscatter_kernel(const int2* __restrict__ runs,
                                                          const int* __restrict__ runcnt,
                                                          int* __restrict__ cursor,
                                                          int2* __restrict__ csr)
{
    int gid = blockIdx.x * 256 + threadIdx.x;
    if (gid >= P_ * MAXR_) return;
    int pixq = gid / MAXR_;
    int slot = gid - pixq * MAXR_;
    if (slot >= runcnt[pixq]) return;
    int2 e = runs[gid];
    int pos = atomicAdd(&cursor[e.x], 1);
    csr[pos] = make_int2(pixq, e.y);
}

// ============ Phase 4: per-voxel gather (no atomics) ============
// 16 consecutive voxels per block; thread t: voxel v0+(t&15), channels (t>>4)+16j
__global__ __launch_bounds__(256) void gather_kernel(const int2* __restrict__ csr,
                                                     const int* __restrict__ start,
                                                     const float* __restrict__ featT,
                                                     float* __restrict__ outp)
{
    int tid = threadIdx.x;
    int vi = tid & 15;
    int cbase = tid >> 4;
    int v = blockIdx.x * 16 + vi;
    int s = start[v];
    int e = start[v + 1];
    float a0 = 0.f, a1 = 0.f, a2 = 0.f, a3 = 0.f, a4 = 0.f;
    for (int i = s; i < e; ++i) {
        int2 ent = csr[i];
        float wgt = __int_as_float(ent.y);
        const float* f = featT + (size_t)ent.x * C_ + cbase;
        a0 += wgt * f[0];
        a1 += wgt * f[16];
        a2 += wgt * f[32];
        a3 += wgt * f[48];
        a4 += wgt * f[64];
    }
    outp[(size_t)(cbase +  0) * NPIX_ + v] = a0;
    outp[(size_t)(cbase + 16) * NPIX_ + v] = a1;
    outp[(size_t)(cbase + 32) * NPIX_ + v] = a2;
    outp[(size_t)(cbase + 48) * NPIX_ + v] = a3;
    outp[(size_t)(cbase + 64) * NPIX_ + v] = a4;
}

// ================= fallback path (round-1 style, if ws too small) =================
__global__ void prep_mats_kernel(const float* __restrict__ rots,
                                 const float* __restrict__ trans,
                                 const float* __restrict__ intrins,
                                 const float* __restrict__ post_rots,
                                 const float* __restrict__ post_trans,
                                 float* __restrict__ mats) {
    int bn = threadIdx.x;
    if (bn >= BN_) return;
    float ip[9], ii[9];
    inv3(post_rots + bn * 9, ip);
    inv3(intrins + bn * 9, ii);
    const float* ro = rots + bn * 9;
    float* out = mats + bn * 24;
    #pragma unroll
    for (int r = 0; r < 3; ++r)
        #pragma unroll
        for (int c = 0; c < 3; ++c)
            out[9 + r * 3 + c] = ro[r * 3 + 0] * ii[0 * 3 + c] +
                                 ro[r * 3 + 1] * ii[1 * 3 + c] +
                                 ro[r * 3 + 2] * ii[2 * 3 + c];
    #pragma unroll
    for (int k = 0; k < 9; ++k) out[k] = ip[k];
    #pragma unroll
    for (int k = 0; k < 3; ++k) { out[18 + k] = post_trans[bn * 3 + k]; out[21 + k] = trans[bn * 3 + k]; }
}

__global__ __launch_bounds__(128) void scatter_kernel(const float* __restrict__ img_feat,
                                                      const float* __restrict__ depth_digit,
                                                      const float* __restrict__ mats,
                                                      float* __restrict__ outp) {
    int blk = blockIdx.x;
    int w  = blk % WF_;
    int h  = (blk / WF_) % HF_;
    int bn = blk / HW_;
    int b  = bn / N_;
    int tid = threadIdx.x;
    __shared__ float sm[24];
    __shared__ float s_feat[C_];
    __shared__ float s_prob[D_];
    __shared__ int   s_vox[D_];
    __shared__ float s_red[128];
    __shared__ float s_mw[D_];
    __shared__ int   s_mvox[D_];
    __shared__ int   s_cnt;
    if (tid < 24) sm[tid] = mats[bn * 24 + tid];
    if (tid < C_) s_feat[tid] = img_feat[((size_t)bn * C_ + tid) * HW_ + h * WF_ + w];
    float logit = -INFINITY;
    if (tid < D_) logit = depth_digit[((size_t)bn * D_ + tid) * HW_ + h * WF_ + w];
    s_red[tid] = logit;
    __syncthreads();
    #pragma unroll
    for (int s = 64; s > 0; s >>= 1) {
        if (tid < s) s_red[tid] = fmaxf(s_red[tid], s_red[tid + s]);
        __syncthreads();
    }
    float mx = s_red[0];
    __syncthreads();
    float e = (tid < D_) ? __expf(logit - mx) : 0.0f;
    s_red[tid] = e;
    __syncthreads();
    #pragma unroll
    for (int s = 64; s > 0; s >>= 1) {
        if (tid < s) s_red[tid] += s_red[tid + s];
        __syncthreads();
    }
    float inv_sum = 1.0f / s_red[0];
    if (tid < D_) s_prob[tid] = e * inv_sum;
    if (tid < D_) {
        float dval = 2.0f + 0.5f * (float)tid;
        float xs = (float)((double)w * (703.0 / 43.0));
        float ys = (float)((double)h * 17.0);
        const float* ip  = sm;
        const float* cmb = sm + 9;
        const float* pt  = sm + 18;
        const float* tr  = sm + 21;
        float p0x = xs - pt[0], p0y = ys - pt[1], p0z = dval - pt[2];
        float p1x = ip[0] * p0x + ip[1] * p0y + ip[2] * p0z;
        float p1y = ip[3] * p0x + ip[4] * p0y + ip[5] * p0z;
        float p1z = ip[6] * p0x + ip[7] * p0y + ip[8] * p0z;
        float qx = p1x * p1z, qy = p1y * p1z, qz = p1z;
        float rx = cmb[0] * qx + cmb[1] * qy + cmb[2] * qz + tr[0];
        float ry = cmb[3] * qx + cmb[4] * qy + cmb[5] * qz + tr[1];
        float rz = cmb[6] * qx + cmb[7] * qy + cmb[8] * qz + tr[2];
        int ix = (int)((rx + 51.2f) / 0.8f);
        int iy = (int)((ry + 51.2f) / 0.8f);
        int iz = (int)((rz + 10.0f) / 20.0f);
        bool val = (ix >= 0) && (ix < NX_) && (iy >= 0) && (iy < NY_) && (iz >= 0) && (iz < NZ_);
        s_vox[tid] = val ? ((iz * NX_ + ix) * NY_ + iy) : -1;
    }
    __syncthreads();
    if (tid == 0) {
        int cnt = 0, last = -1;
        float wsum = 0.0f;
        for (int d0 = 0; d0 < D_; ++d0) {
            int v = s_vox[d0];
            if (v < 0) continue;
            if (v == last) { wsum += s_prob[d0]; }
            else {
                if (last >= 0) { s_mvox[cnt] = last; s_mw[cnt] = wsum; ++cnt; }
                last = v; wsum = s_prob[d0];
            }
        }
        if (last >= 0) { s_mvox[cnt] = last; s_mw[cnt] = wsum; ++cnt; }
        s_cnt = cnt;
    }
    __syncthreads();
    int cnt = s_cnt;
    int total = cnt * C_;
    for (int k = tid; k < total; k += 128) {
        int i = k / C_;
        int c = k - i * C_;
        int pixv = s_mvox[i];
        atomicAdd(outp + ((size_t)(b * C_ + c)) * NPIX_ + pixv, s_mw[i] * s_feat[c]);
    }
}

extern "C" void kernel_launch(void* const* d_in, const int* in_sizes, int n_in,
                              void* d_out, int out_size, void* d_ws, size_t ws_size,
                              hipStream_t stream) {
    const float* rots        = (const float*)d_in[1];
    const float* trans       = (const float*)d_in[2];
    const float* intrins     = (const float*)d_in[3];
    const float* post_rots   = (const float*)d_in[4];
    const float* post_trans  = (const float*)d_in[5];
    const float* img_feat    = (const float*)d_in[6];
    const float* depth_digit = (const float*)d_in[7];
    float* outp = (float*)d_out;

    // workspace layout (256B-aligned segments)
    const size_t featT_b  = (size_t)P_ * C_ * 4;          // 1,351,680
    const size_t runs_b   = (size_t)P_ * MAXR_ * 8;       // 3,784,704
    const size_t runcnt_b = (size_t)P_ * 4;               // 16,896
    const size_t hist_b   = (size_t)NPIX_ * 4;            // 65,536
    const size_t start_b  = ((size_t)(NPIX_ + 1) * 4 + 255) & ~(size_t)255;
    const size_t cursor_b = (size_t)NPIX_ * 4;
    const size_t csr_b    = (size_t)P_ * MAXR_ * 8;
    const size_t need = featT_b + runs_b + runcnt_b + hist_b + start_b + cursor_b + csr_b;

    if (ws_size >= need) {
        char* p = (char*)d_ws;
        float* featT = (float*)p;  p += featT_b;
        int2*  runs  = (int2*)p;   p += runs_b;
        int*   runcnt= (int*)p;    p += runcnt_b;
        int*   hist  = (int*)p;    p += hist_b;
        int*   start = (int*)p;    p += start_b;
        int*   cursor= (int*)p;    p += cursor_b;
        int2*  csr   = (int2*)p;

        hipMemsetAsync(hist, 0, hist_b, stream);
        pixel_kernel<<<P_, 128, 0, stream>>>(rots, trans, intrins, post_rots, post_trans,
                                             img_feat, depth_digit, featT, runs, runcnt, hist);
        scan_kernel<<<1, 1024, 0, stream>>>(hist, start, cursor);
        sortscatter_kernel<<<(P_ * MAXR_ + 255) / 256, 256, 0, stream>>>(runs, runcnt, cursor, csr);
        gather_kernel<<<NPIX_ / 16, 256, 0, stream>>>(csr, start, featT, outp);
    } else {
        // fallback: direct atomic scatter into output layout
        float* mats = (float*)d_ws;
        prep_mats_kernel<<<1, 64, 0, stream>>>(rots, trans, intrins, post_rots, post_trans, mats);
        hipMemsetAsync(outp, 0, (size_t)out_size * sizeof(float), stream);
        scatter_kernel<<<P_, 128, 0, stream>>>(img_feat, depth_digit, mats, outp);
    }
}